// Round 1
// baseline (619.907 us; speedup 1.0000x reference)
//
#include <hip/hip_runtime.h>
#include <stdint.h>

#define BATCH 256
#define T_PREVN 128
#define T_CURN 129
#define N_COV 30
#define N_TREAT 57
#define N_CONF 5
#define HID 128
#define D_IN 87
#define D_CELL 92
#define GATES 512            // 4*H
#define KTOT 220             // D_CELL + H
#define PRED_N (T_CURN*BATCH)        // 33024
#define CONF_OFF (PRED_N*N_TREAT)    // 1882368

typedef _Float16 h2 __attribute__((ext_vector_type(2)));

__device__ inline float rcp_fast(float x){
#if __has_builtin(__builtin_amdgcn_rcpf)
    return __builtin_amdgcn_rcpf(x);
#else
    return 1.0f / x;
#endif
}
__device__ inline float sigmoid_f(float x){ return rcp_fast(1.0f + __expf(-x)); }
__device__ inline float tanh_f(float x){ return 1.0f - 2.0f*rcp_fast(1.0f + __expf(2.0f*x)); }

__device__ inline float dot2f(h2 a, h2 b, float c){
#if __has_builtin(__builtin_amdgcn_fdot2)
    return __builtin_amdgcn_fdot2(a, b, c, false);
#else
    return c + (float)a.x*(float)b.x + (float)a.y*(float)b.y;
#endif
}
__device__ inline unsigned short f2us(float v){
    _Float16 h = (_Float16)v;
    return __builtin_bit_cast(unsigned short, h);
}
__device__ inline h2 us2h2(unsigned int u){
    return __builtin_bit_cast(h2, u);
}

// One block per batch element. 1024 threads: thread = (gate in [0,512), khalf).
// Activation vector v (fp16) layout in LDS, padded per half to 112 halfs:
//   logical kv: [0,87) = x_t, [87,92) = z_{t-1}, [92,220) = h_{t-1}
//   pos(kv) = kv < 110 ? kv : kv+2 ; pads {110,111,222,223} = 0
__global__ __launch_bounds__(1024) void lstm_scan(
    const float* __restrict__ pc, const float* __restrict__ pt,
    const float* __restrict__ init_input, const float* __restrict__ h0,
    const float* __restrict__ c0, const float* __restrict__ z0,
    const float* __restrict__ W_ih, const float* __restrict__ W_hh,
    const float* __restrict__ b_ih, const float* __restrict__ b_hh,
    const float* __restrict__ W_z, const float* __restrict__ b_z,
    float* __restrict__ zs_out)
{
    const int b    = blockIdx.x;
    const int tid  = threadIdx.x;
    const int gate = tid & 511;
    const int half = tid >> 9;

    __shared__ alignas(16) unsigned short v16[224];
    __shared__ float part[512];
    __shared__ float gbuf[512];
    __shared__ float hbuf[128];
    __shared__ float wzs[5*128];

    // ---- load this thread's 110 weights (fp16 pairs) ----
    h2 w[56];
    {
        const int kbase = half * 110;
        #pragma unroll
        for (int i = 0; i < 55; i++){
            const int k0 = kbase + 2*i;
            const int k1 = k0 + 1;
            float f0 = (k0 < D_CELL) ? W_ih[gate*D_CELL + k0] : W_hh[gate*HID + (k0 - D_CELL)];
            float f1 = (k1 < D_CELL) ? W_ih[gate*D_CELL + k1] : W_hh[gate*HID + (k1 - D_CELL)];
            h2 p; p.x = (_Float16)f0; p.y = (_Float16)f1;
            w[i] = p;
        }
        h2 zz; zz.x = (_Float16)0.0f; zz.y = (_Float16)0.0f;
        w[55] = zz;
    }
    const float bias = (tid < GATES) ? (b_ih[tid] + b_hh[tid]) : 0.0f;
    float c = (tid < HID) ? c0[tid] : 0.0f;

    if (tid < 5*128) wzs[tid] = W_z[tid];

    // ---- init v16 ----
    if (tid < KTOT){
        const int kv = tid;
        float val;
        if (kv < D_IN)        val = init_input[kv];
        else if (kv < D_CELL) val = z0[kv - D_IN];
        else                  val = h0[kv - D_CELL];
        const int pos = (kv < 110) ? kv : kv + 2;
        v16[pos] = f2us(val);
    } else if (tid < 224){
        const int p = (tid == 220) ? 110 : (tid == 221) ? 111 : (tid == 222) ? 222 : 223;
        v16[p] = 0;
    }
    __syncthreads();

    const int xthr = tid - 896;   // threads 896..982 prefetch next x (87 vals)

    for (int t = 0; t < T_CURN; t++){
        // prefetch x_{t+1} = concat(pc[b][t], pt[b][t]) into a register
        float xv = 0.0f;
        const bool xa = (xthr >= 0) && (xthr < D_IN) && (t < T_PREVN);
        if (xa){
            xv = (xthr < N_COV) ? pc[(b*T_PREVN + t)*N_COV + xthr]
                                : pt[(b*T_PREVN + t)*N_TREAT + (xthr - N_COV)];
        }

        // ---- GEMV partial: my half of the K=220 dot for my gate ----
        float acc = 0.0f;
        const uint4* vb = (const uint4*)(v16 + half*112);
        #pragma unroll
        for (int i = 0; i < 14; i++){
            uint4 q = vb[i];
            acc = dot2f(w[4*i+0], us2h2(q.x), acc);
            acc = dot2f(w[4*i+1], us2h2(q.y), acc);
            acc = dot2f(w[4*i+2], us2h2(q.z), acc);
            acc = dot2f(w[4*i+3], us2h2(q.w), acc);
        }
        if (half) part[gate] = acc;
        __syncthreads();

        if (tid < GATES) gbuf[tid] = acc + part[tid] + bias;
        if (xa) v16[xthr] = f2us(xv);          // pos(kv<87) = kv
        __syncthreads();

        if (tid < HID){
            const float gi = gbuf[tid];
            const float gf = gbuf[128 + tid];
            const float gg = gbuf[256 + tid];
            const float go = gbuf[384 + tid];
            c = sigmoid_f(gf)*c + sigmoid_f(gi)*tanh_f(gg);
            const float h = sigmoid_f(go)*tanh_f(c);
            hbuf[tid] = h;
            const int kv = D_CELL + tid;
            const int pos = (kv < 110) ? kv : kv + 2;
            v16[pos] = f2us(h);
        }
        __syncthreads();

        if (tid >= 128 && tid < 448){
            const int zi   = (tid - 128) >> 6;
            const int lane = tid & 63;
            float s = hbuf[lane]      * wzs[zi*128 + lane]
                    + hbuf[lane + 64] * wzs[zi*128 + lane + 64];
            s += __shfl_down(s, 32);
            s += __shfl_down(s, 16);
            s += __shfl_down(s, 8);
            s += __shfl_down(s, 4);
            s += __shfl_down(s, 2);
            s += __shfl_down(s, 1);
            if (lane == 0){
                const float z = s + b_z[zi];
                zs_out[(t*BATCH + b)*N_CONF + zi] = z;
                v16[D_IN + zi] = f2us(z);      // pos 87..91
            }
        }
        __syncthreads();
    }
}

// Decoder: block = (t in [0,129), treat in [0,57)), 256 threads = 256 batch rows.
// preds[n,treat] = dot(w2_t, leaky(W1_t^T m + b1_t)) + b2_t, m = [z(5), cov(30), 0]
__global__ __launch_bounds__(256) void decoder(
    const float* __restrict__ cc, const float* __restrict__ zs,
    const float* __restrict__ dW1, const float* __restrict__ db1,
    const float* __restrict__ dW2, const float* __restrict__ db2,
    float* __restrict__ preds)
{
    const int t     = blockIdx.x;
    const int treat = blockIdx.y;
    const int tid   = threadIdx.x;

    __shared__ alignas(16) float w1t[128*36];  // [f][c] padded to 36
    __shared__ float b1s[128];
    __shared__ float w2s[128];

    for (int it = tid; it < 35*128; it += 256){
        const int cidx = it >> 7;
        const int f    = it & 127;
        w1t[f*36 + cidx] = dW1[(treat*35 + cidx)*128 + f];
    }
    if (tid < 128){
        b1s[tid] = db1[treat*128 + tid];
        w2s[tid] = dW2[treat*128 + tid];
        w1t[tid*36 + 35] = 0.0f;
    }
    __syncthreads();

    const int n = t*BATCH + tid;     // tid == batch index b
    float m[36];
    #pragma unroll
    for (int j = 0; j < N_CONF; j++) m[j] = zs[n*N_CONF + j];
    #pragma unroll
    for (int j = 0; j < N_COV; j++)  m[N_CONF + j] = cc[(tid*T_CURN + t)*N_COV + j];
    m[35] = 0.0f;

    const float b2 = db2[treat];
    float pred = 0.0f;
    for (int f = 0; f < 128; f++){
        float a = b1s[f];
        const float4* wr = (const float4*)(w1t + f*36);
        #pragma unroll
        for (int cq = 0; cq < 9; cq++){
            const float4 v = wr[cq];
            a += m[cq*4+0]*v.x + m[cq*4+1]*v.y + m[cq*4+2]*v.z + m[cq*4+3]*v.w;
        }
        a = (a > 0.0f) ? a : 0.01f*a;
        pred += a * w2s[f];
    }
    preds[n*N_TREAT + treat] = pred + b2;
}

extern "C" void kernel_launch(void* const* d_in, const int* in_sizes, int n_in,
                              void* d_out, int out_size, void* d_ws, size_t ws_size,
                              hipStream_t stream)
{
    const float* pc   = (const float*)d_in[0];
    const float* pt   = (const float*)d_in[1];
    const float* cc   = (const float*)d_in[2];
    const float* init = (const float*)d_in[3];
    const float* h0   = (const float*)d_in[4];
    const float* c0   = (const float*)d_in[5];
    const float* z0   = (const float*)d_in[6];
    const float* W_ih = (const float*)d_in[7];
    const float* W_hh = (const float*)d_in[8];
    const float* b_ih = (const float*)d_in[9];
    const float* b_hh = (const float*)d_in[10];
    const float* W_z  = (const float*)d_in[11];
    const float* b_z  = (const float*)d_in[12];
    const float* dW1  = (const float*)d_in[13];
    const float* db1  = (const float*)d_in[14];
    const float* dW2  = (const float*)d_in[15];
    const float* db2  = (const float*)d_in[16];

    float* preds = (float*)d_out;
    float* zs    = (float*)d_out + CONF_OFF;   // confounders region == zs flat

    lstm_scan<<<BATCH, 1024, 0, stream>>>(pc, pt, init, h0, c0, z0,
                                          W_ih, W_hh, b_ih, b_hh, W_z, b_z, zs);
    decoder<<<dim3(T_CURN, N_TREAT), 256, 0, stream>>>(cc, zs, dW1, db1, dW2, db2, preds);
}

// Round 2
// 348.648 us; speedup vs baseline: 1.7780x; 1.7780x over previous
//
#include <hip/hip_runtime.h>
#include <stdint.h>

#define BATCH 256
#define T_PREVN 128
#define T_CURN 129
#define N_COV 30
#define N_TREAT 57
#define N_CONF 5
#define HID 128
#define D_IN 87
#define D_CELL 92
#define GATES 512            // 4*H
#define KTOT 220             // D_CELL + H
#define PRED_N (T_CURN*BATCH)        // 33024
#define CONF_OFF (PRED_N*N_TREAT)    // 1882368
#define WS_NEED (57*8*2*64*8*2)      // 933888 bytes of f16 B-fragments

typedef _Float16 h2 __attribute__((ext_vector_type(2)));
typedef _Float16 h8 __attribute__((ext_vector_type(8)));
typedef float f32x4 __attribute__((ext_vector_type(4)));

__device__ inline float rcp_fast(float x){
#if __has_builtin(__builtin_amdgcn_rcpf)
    return __builtin_amdgcn_rcpf(x);
#else
    return 1.0f / x;
#endif
}
__device__ inline float sigmoid_f(float x){ return rcp_fast(1.0f + __expf(-x)); }
__device__ inline float tanh_f(float x){ return 1.0f - 2.0f*rcp_fast(1.0f + __expf(2.0f*x)); }

__device__ inline float dot2f(h2 a, h2 b, float c){
#if __has_builtin(__builtin_amdgcn_fdot2)
    return __builtin_amdgcn_fdot2(a, b, c, false);
#else
    return c + (float)a.x*(float)b.x + (float)a.y*(float)b.y;
#endif
}
__device__ inline unsigned short f2us(float v){
    _Float16 h = (_Float16)v;
    return __builtin_bit_cast(unsigned short, h);
}
__device__ inline h2 us2h2(unsigned int u){
    return __builtin_bit_cast(h2, u);
}

// ---------------- LSTM scan (unchanged from R1; ~150us) ----------------
__global__ __launch_bounds__(1024) void lstm_scan(
    const float* __restrict__ pc, const float* __restrict__ pt,
    const float* __restrict__ init_input, const float* __restrict__ h0,
    const float* __restrict__ c0, const float* __restrict__ z0,
    const float* __restrict__ W_ih, const float* __restrict__ W_hh,
    const float* __restrict__ b_ih, const float* __restrict__ b_hh,
    const float* __restrict__ W_z, const float* __restrict__ b_z,
    float* __restrict__ zs_out)
{
    const int b    = blockIdx.x;
    const int tid  = threadIdx.x;
    const int gate = tid & 511;
    const int half = tid >> 9;

    __shared__ alignas(16) unsigned short v16[224];
    __shared__ float part[512];
    __shared__ float gbuf[512];
    __shared__ float hbuf[128];
    __shared__ float wzs[5*128];

    h2 w[56];
    {
        const int kbase = half * 110;
        #pragma unroll
        for (int i = 0; i < 55; i++){
            const int k0 = kbase + 2*i;
            const int k1 = k0 + 1;
            float f0 = (k0 < D_CELL) ? W_ih[gate*D_CELL + k0] : W_hh[gate*HID + (k0 - D_CELL)];
            float f1 = (k1 < D_CELL) ? W_ih[gate*D_CELL + k1] : W_hh[gate*HID + (k1 - D_CELL)];
            h2 p; p.x = (_Float16)f0; p.y = (_Float16)f1;
            w[i] = p;
        }
        h2 zz; zz.x = (_Float16)0.0f; zz.y = (_Float16)0.0f;
        w[55] = zz;
    }
    const float bias = (tid < GATES) ? (b_ih[tid] + b_hh[tid]) : 0.0f;
    float c = (tid < HID) ? c0[tid] : 0.0f;

    if (tid < 5*128) wzs[tid] = W_z[tid];

    if (tid < KTOT){
        const int kv = tid;
        float val;
        if (kv < D_IN)        val = init_input[kv];
        else if (kv < D_CELL) val = z0[kv - D_IN];
        else                  val = h0[kv - D_CELL];
        const int pos = (kv < 110) ? kv : kv + 2;
        v16[pos] = f2us(val);
    } else if (tid < 224){
        const int p = (tid == 220) ? 110 : (tid == 221) ? 111 : (tid == 222) ? 222 : 223;
        v16[p] = 0;
    }
    __syncthreads();

    const int xthr = tid - 896;

    for (int t = 0; t < T_CURN; t++){
        float xv = 0.0f;
        const bool xa = (xthr >= 0) && (xthr < D_IN) && (t < T_PREVN);
        if (xa){
            xv = (xthr < N_COV) ? pc[(b*T_PREVN + t)*N_COV + xthr]
                                : pt[(b*T_PREVN + t)*N_TREAT + (xthr - N_COV)];
        }

        float acc = 0.0f;
        const uint4* vb = (const uint4*)(v16 + half*112);
        #pragma unroll
        for (int i = 0; i < 14; i++){
            uint4 q = vb[i];
            acc = dot2f(w[4*i+0], us2h2(q.x), acc);
            acc = dot2f(w[4*i+1], us2h2(q.y), acc);
            acc = dot2f(w[4*i+2], us2h2(q.z), acc);
            acc = dot2f(w[4*i+3], us2h2(q.w), acc);
        }
        if (half) part[gate] = acc;
        __syncthreads();

        if (tid < GATES) gbuf[tid] = acc + part[tid] + bias;
        if (xa) v16[xthr] = f2us(xv);
        __syncthreads();

        if (tid < HID){
            const float gi = gbuf[tid];
            const float gf = gbuf[128 + tid];
            const float gg = gbuf[256 + tid];
            const float go = gbuf[384 + tid];
            c = sigmoid_f(gf)*c + sigmoid_f(gi)*tanh_f(gg);
            const float h = sigmoid_f(go)*tanh_f(c);
            hbuf[tid] = h;
            const int kv = D_CELL + tid;
            const int pos = (kv < 110) ? kv : kv + 2;
            v16[pos] = f2us(h);
        }
        __syncthreads();

        if (tid >= 128 && tid < 448){
            const int zi   = (tid - 128) >> 6;
            const int lane = tid & 63;
            float s = hbuf[lane]      * wzs[zi*128 + lane]
                    + hbuf[lane + 64] * wzs[zi*128 + lane + 64];
            s += __shfl_down(s, 32);
            s += __shfl_down(s, 16);
            s += __shfl_down(s, 8);
            s += __shfl_down(s, 4);
            s += __shfl_down(s, 2);
            s += __shfl_down(s, 1);
            if (lane == 0){
                const float z = s + b_z[zi];
                zs_out[(t*BATCH + b)*N_CONF + zi] = z;
                v16[D_IN + zi] = f2us(z);
            }
        }
        __syncthreads();
    }
}

// ---------------- W1 prepack: f32 -> f16 B-fragments in ws ----------------
// frag (treat, ft, ks): lane l, elem j holds W1[k][col], k = ks*32 + (l>>4)*8 + j
// (zero for k>=35), col = ft*16 + (l&15).  Linear: wsh[tid*8 + j].
__global__ __launch_bounds__(256) void prepack_w1(const float* __restrict__ dW1,
                                                  _Float16* __restrict__ wsh)
{
    const int tid = blockIdx.x*256 + threadIdx.x;   // 228*256 == 57*1024 exactly
    const int treat = tid >> 10;
    const int r     = tid & 1023;
    const int ft    = r >> 7;
    const int ks    = (r >> 6) & 1;
    const int l     = r & 63;
    const int col   = ft*16 + (l & 15);
    const int kb    = ks*32 + ((l >> 4) << 3);
    h8 v;
    #pragma unroll
    for (int j = 0; j < 8; j++){
        const int k = kb + j;
        v[j] = (k < 35) ? (_Float16)dW1[(treat*35 + k)*128 + col] : (_Float16)0.0f;
    }
    *(h8*)(wsh + (size_t)tid*8) = v;
}

// ---------------- MFMA decoder ----------------
// block = 64 rows (4 waves x 16 rows), grid = 516.  A = m (f16, LDS), B = ws frags.
__global__ __launch_bounds__(256) void decoder_mfma(
    const float* __restrict__ cc, const float* __restrict__ zs,
    const _Float16* __restrict__ wsh,
    const float* __restrict__ db1, const float* __restrict__ dW2,
    const float* __restrict__ db2, float* __restrict__ preds)
{
    __shared__ alignas(16) _Float16 m_lds[64*72];   // [row][k] k padded to 72

    const int tid  = threadIdx.x;
    const int base = blockIdx.x * 64;
    const int t    = base >> 8;                     // 64-row blocks never cross t

    for (int idx = tid; idx < 64*72; idx += 256){
        const int r = idx / 72;
        const int j = idx - r*72;
        const int n = base + r;
        const int b = n & 255;
        float v = 0.0f;
        if (j < 5)       v = zs[n*N_CONF + j];
        else if (j < 35) v = cc[(b*T_CURN + t)*N_COV + (j - 5)];
        m_lds[r*72 + j] = (_Float16)v;
    }
    __syncthreads();

    const int w    = tid >> 6;
    const int l    = tid & 63;
    const int row  = l & 15;
    const int quad = l >> 4;

    const _Float16* arow = m_lds + (w*16 + row)*72 + quad*8;
    const h8 a0 = *(const h8*)(arow);
    const h8 a1 = *(const h8*)(arow + 32);
    const int nbase = base + w*16 + quad*4;

    for (int treat = 0; treat < 57; treat++){
        const _Float16* bp = wsh + (size_t)treat*8192 + l*8;
        f32x4 pred = {0.0f, 0.0f, 0.0f, 0.0f};
        #pragma unroll
        for (int ft = 0; ft < 8; ft++){
            const h8 b0 = *(const h8*)(bp + ft*1024);
            const h8 b1 = *(const h8*)(bp + ft*1024 + 512);
            f32x4 acc = {0.0f, 0.0f, 0.0f, 0.0f};
            acc = __builtin_amdgcn_mfma_f32_16x16x32_f16(a0, b0, acc, 0, 0, 0);
            acc = __builtin_amdgcn_mfma_f32_16x16x32_f16(a1, b1, acc, 0, 0, 0);
            const int col = ft*16 + row;
            const float hb1 = db1[treat*128 + col];
            const float hw2 = dW2[treat*128 + col];
            #pragma unroll
            for (int r = 0; r < 4; r++){
                float hd = acc[r] + hb1;
                hd = (hd > 0.0f) ? hd : 0.01f*hd;
                pred[r] += hd * hw2;
            }
        }
        #pragma unroll
        for (int r = 0; r < 4; r++){
            float s = pred[r];
            s += __shfl_xor(s, 1);
            s += __shfl_xor(s, 2);
            s += __shfl_xor(s, 4);
            s += __shfl_xor(s, 8);
            pred[r] = s;
        }
        if (row == 0){
            const float b2 = db2[treat];
            #pragma unroll
            for (int r = 0; r < 4; r++)
                preds[(size_t)(nbase + r)*N_TREAT + treat] = pred[r] + b2;
        }
    }
}

// ---------------- fp32 fallback decoder (only if ws too small) ----------------
__global__ __launch_bounds__(256) void decoder_fallback(
    const float* __restrict__ cc, const float* __restrict__ zs,
    const float* __restrict__ dW1, const float* __restrict__ db1,
    const float* __restrict__ dW2, const float* __restrict__ db2,
    float* __restrict__ preds)
{
    const int t     = blockIdx.x;
    const int treat = blockIdx.y;
    const int tid   = threadIdx.x;

    __shared__ alignas(16) float w1t[128*36];
    __shared__ float b1s[128];
    __shared__ float w2s[128];

    for (int it = tid; it < 35*128; it += 256){
        const int cidx = it >> 7;
        const int f    = it & 127;
        w1t[f*36 + cidx] = dW1[(treat*35 + cidx)*128 + f];
    }
    if (tid < 128){
        b1s[tid] = db1[treat*128 + tid];
        w2s[tid] = dW2[treat*128 + tid];
        w1t[tid*36 + 35] = 0.0f;
    }
    __syncthreads();

    const int n = t*BATCH + tid;
    float m[36];
    #pragma unroll
    for (int j = 0; j < N_CONF; j++) m[j] = zs[n*N_CONF + j];
    #pragma unroll
    for (int j = 0; j < N_COV; j++)  m[N_CONF + j] = cc[(tid*T_CURN + t)*N_COV + j];
    m[35] = 0.0f;

    const float b2 = db2[treat];
    float pred = 0.0f;
    for (int f = 0; f < 128; f++){
        float a = b1s[f];
        const float4* wr = (const float4*)(w1t + f*36);
        #pragma unroll
        for (int cq = 0; cq < 9; cq++){
            const float4 v = wr[cq];
            a += m[cq*4+0]*v.x + m[cq*4+1]*v.y + m[cq*4+2]*v.z + m[cq*4+3]*v.w;
        }
        a = (a > 0.0f) ? a : 0.01f*a;
        pred += a * w2s[f];
    }
    preds[n*N_TREAT + treat] = pred + b2;
}

extern "C" void kernel_launch(void* const* d_in, const int* in_sizes, int n_in,
                              void* d_out, int out_size, void* d_ws, size_t ws_size,
                              hipStream_t stream)
{
    const float* pc   = (const float*)d_in[0];
    const float* pt   = (const float*)d_in[1];
    const float* cc   = (const float*)d_in[2];
    const float* init = (const float*)d_in[3];
    const float* h0   = (const float*)d_in[4];
    const float* c0   = (const float*)d_in[5];
    const float* z0   = (const float*)d_in[6];
    const float* W_ih = (const float*)d_in[7];
    const float* W_hh = (const float*)d_in[8];
    const float* b_ih = (const float*)d_in[9];
    const float* b_hh = (const float*)d_in[10];
    const float* W_z  = (const float*)d_in[11];
    const float* b_z  = (const float*)d_in[12];
    const float* dW1  = (const float*)d_in[13];
    const float* db1  = (const float*)d_in[14];
    const float* dW2  = (const float*)d_in[15];
    const float* db2  = (const float*)d_in[16];

    float* preds = (float*)d_out;
    float* zs    = (float*)d_out + CONF_OFF;

    const bool use_mfma = (ws_size >= (size_t)WS_NEED);

    if (use_mfma)
        prepack_w1<<<228, 256, 0, stream>>>(dW1, (_Float16*)d_ws);

    lstm_scan<<<BATCH, 1024, 0, stream>>>(pc, pt, init, h0, c0, z0,
                                          W_ih, W_hh, b_ih, b_hh, W_z, b_z, zs);

    if (use_mfma)
        decoder_mfma<<<516, 256, 0, stream>>>(cc, zs, (const _Float16*)d_ws,
                                              db1, dW2, db2, preds);
    else
        decoder_fallback<<<dim3(T_CURN, N_TREAT), 256, 0, stream>>>(
            cc, zs, dW1, db1, dW2, db2, preds);
}

// Round 3
// 256.240 us; speedup vs baseline: 2.4192x; 1.3606x over previous
//
#include <hip/hip_runtime.h>
#include <stdint.h>

#define BATCH 256
#define T_PREVN 128
#define T_CURN 129
#define N_COV 30
#define N_TREAT 57
#define N_CONF 5
#define HID 128
#define D_IN 87
#define D_CELL 92
#define GATES 512            // 4*H
#define PRED_N (T_CURN*BATCH)        // 33024
#define CONF_OFF (PRED_N*N_TREAT)    // 1882368
#define WS_NEED (57*8*2*64*8*2)      // 933888 bytes of f16 B-fragments

typedef _Float16 h2 __attribute__((ext_vector_type(2)));
typedef _Float16 h8 __attribute__((ext_vector_type(8)));
typedef float f32x4 __attribute__((ext_vector_type(4)));

__device__ inline float rcp_fast(float x){
#if __has_builtin(__builtin_amdgcn_rcpf)
    return __builtin_amdgcn_rcpf(x);
#else
    return 1.0f / x;
#endif
}
__device__ inline float sigmoid_f(float x){ return rcp_fast(1.0f + __expf(-x)); }
__device__ inline float tanh_f(float x){ return 1.0f - 2.0f*rcp_fast(1.0f + __expf(2.0f*x)); }

__device__ inline float dot2f(h2 a, h2 b, float c){
#if __has_builtin(__builtin_amdgcn_fdot2)
    return __builtin_amdgcn_fdot2(a, b, c, false);
#else
    return c + (float)a.x*(float)b.x + (float)a.y*(float)b.y;
#endif
}
__device__ inline unsigned short f2us(float v){
    _Float16 h = (_Float16)v;
    return __builtin_bit_cast(unsigned short, h);
}
__device__ inline h2 us2h2(unsigned int u){
    return __builtin_bit_cast(h2, u);
}

// ---------------- LSTM scan, restructured ----------------
// One block per batch element. 1024 threads = 512 gates x 2 k-halves
// (pair = adjacent lanes 2g, 2g+1).  z folded out of the recurrence:
//   W_eff = W_hh + W_ih[:,87:92] @ W_z ; bias_eff = b_ih+b_hh+W_ih[:,87:92]@b_z
//   t==0 correction: delta0 = W_ih[:,87:92] @ (z0 - b_z - W_z@h0)
// v16 layout (halfs): [0..87) x_t, 87 pad, [88..216) h, [216..224) pad.
// even half reads halfs [0,112) (x + h[0..24)), odd reads [112,224) (h[24..128)).
// Loop touches LDS only; all x pre-staged (xall), all h recorded (hall);
// z computed as a post-pass and written to global once.
__global__ __launch_bounds__(1024, 4) void lstm_scan(
    const float* __restrict__ pc, const float* __restrict__ pt,
    const float* __restrict__ init_input, const float* __restrict__ h0,
    const float* __restrict__ c0, const float* __restrict__ z0,
    const float* __restrict__ W_ih, const float* __restrict__ W_hh,
    const float* __restrict__ b_ih, const float* __restrict__ b_hh,
    const float* __restrict__ W_z, const float* __restrict__ b_z,
    float* __restrict__ zs_out)
{
    const int b   = blockIdx.x;
    const int tid = threadIdx.x;
    const int g   = tid >> 1;      // gate 0..511
    const int hf  = tid & 1;       // k-half

    __shared__ alignas(16) unsigned short v16[224];
    __shared__ alignas(16) unsigned short xall[T_CURN*88];   // 22704 B
    __shared__ alignas(16) unsigned short hall[T_CURN*136];  // 35088 B (136 = bank-spread pad)
    __shared__ alignas(16) float gbuf[GATES];
    __shared__ alignas(16) _Float16 wz16[5*HID];
    __shared__ float z0c[5];

    // ---- P1: fold weights into registers, stage xall, init h/c, zh0 ----
    float wzg[5];
    #pragma unroll
    for (int z = 0; z < 5; z++) wzg[z] = W_ih[g*D_CELL + 87 + z];

    float be = b_ih[g] + b_hh[g];
    #pragma unroll
    for (int z = 0; z < 5; z++) be += wzg[z] * b_z[z];

    h2 w[56];
    if (hf == 0){
        #pragma unroll
        for (int i = 0; i < 43; i++){            // halfs 0..85: x pairs
            h2 p; p.x = (_Float16)W_ih[g*D_CELL + 2*i];
                  p.y = (_Float16)W_ih[g*D_CELL + 2*i + 1];
            w[i] = p;
        }
        { h2 p; p.x = (_Float16)W_ih[g*D_CELL + 86]; p.y = (_Float16)0.0f; w[43] = p; }
        #pragma unroll
        for (int i = 44; i < 56; i++){           // halfs 88..111: h units 0..23
            const int u = 2*(i - 44);
            float f0 = W_hh[g*HID + u], f1 = W_hh[g*HID + u + 1];
            #pragma unroll
            for (int z = 0; z < 5; z++){
                f0 += wzg[z]*W_z[z*HID + u];
                f1 += wzg[z]*W_z[z*HID + u + 1];
            }
            h2 p; p.x = (_Float16)f0; p.y = (_Float16)f1;
            w[i] = p;
        }
    } else {
        #pragma unroll
        for (int i = 0; i < 52; i++){            // halfs 112..215: h units 24..127
            const int u = 24 + 2*i;
            float f0 = W_hh[g*HID + u], f1 = W_hh[g*HID + u + 1];
            #pragma unroll
            for (int z = 0; z < 5; z++){
                f0 += wzg[z]*W_z[z*HID + u];
                f1 += wzg[z]*W_z[z*HID + u + 1];
            }
            h2 p; p.x = (_Float16)f0; p.y = (_Float16)f1;
            w[i] = p;
        }
        #pragma unroll
        for (int i = 52; i < 56; i++){ h2 p; p.x=(_Float16)0.f; p.y=(_Float16)0.f; w[i]=p; }
    }

    // stage all x into LDS as f16
    for (int idx = tid; idx < T_CURN*88; idx += 1024){
        const int row = idx / 88;
        const int col = idx - row*88;
        float v = 0.0f;
        if (col < D_IN){
            if (row == 0) v = init_input[col];
            else {
                const int tp = row - 1;
                v = (col < N_COV) ? pc[(b*T_PREVN + tp)*N_COV + col]
                                  : pt[(b*T_PREVN + tp)*N_TREAT + (col - N_COV)];
            }
        }
        xall[idx] = f2us(v);
    }

    float c = 0.0f;
    if (tid < HID){ v16[88 + tid] = f2us(h0[tid]); c = c0[tid]; }
    if (tid >= 216 && tid < 224) v16[tid] = 0;

    if (tid < 5){
        float acc0 = 0.0f, acc1 = 0.0f;
        #pragma unroll 8
        for (int u = 0; u < HID; u += 2){
            acc0 += W_z[tid*HID + u]     * h0[u];
            acc1 += W_z[tid*HID + u + 1] * h0[u + 1];
        }
        z0c[tid] = z0[tid] - b_z[tid] - (acc0 + acc1);
    }
    __syncthreads();

    // ---- P2: x0 into v16, t==0 bias correction ----
    if (tid >= 128 && tid < 216) v16[tid - 128] = xall[tid - 128];
    float b0 = be;
    #pragma unroll
    for (int z = 0; z < 5; z++) b0 += wzg[z] * z0c[z];
    __syncthreads();

    // ---- main loop: 2 barriers/step, LDS only ----
    const unsigned short* vbase = v16 + hf*112;
    for (int t = 0; t < T_CURN; t++){
        float a0 = 0.f, a1 = 0.f, a2 = 0.f, a3 = 0.f;
        #pragma unroll
        for (int i = 0; i < 14; i++){
            const uint4 q = *(const uint4*)(vbase + i*8);
            a0 = dot2f(w[4*i+0], us2h2(q.x), a0);
            a1 = dot2f(w[4*i+1], us2h2(q.y), a1);
            a2 = dot2f(w[4*i+2], us2h2(q.z), a2);
            a3 = dot2f(w[4*i+3], us2h2(q.w), a3);
        }
        float s = (a0 + a1) + (a2 + a3);
        s += __shfl_xor(s, 1);
        if (hf == 0) gbuf[g] = s + ((t == 0) ? b0 : be);
        __syncthreads();

        if (tid < HID){
            const float gi = gbuf[tid];
            const float gf = gbuf[128 + tid];
            const float gg = gbuf[256 + tid];
            const float go = gbuf[384 + tid];
            c = sigmoid_f(gf)*c + sigmoid_f(gi)*tanh_f(gg);
            const float h = sigmoid_f(go)*tanh_f(c);
            const unsigned short hu = f2us(h);
            v16[88 + tid] = hu;
            hall[t*136 + tid] = hu;
        } else if (tid < 216){
            if (t < T_PREVN) v16[tid - 128] = xall[(t + 1)*88 + (tid - 128)];
        }
        __syncthreads();
    }

    // ---- post-pass: z_t = W_z h_t + b_z for all t, single global write ----
    for (int i = tid; i < 5*HID; i += 1024) wz16[i] = (_Float16)W_z[i];
    __syncthreads();

    if (tid < T_CURN*N_CONF){
        const int t  = tid / 5;
        const int zi = tid - t*5;
        const uint4* hr = (const uint4*)(hall + t*136);
        const uint4* wr = (const uint4*)(wz16 + zi*HID);
        float a0 = 0.f, a1 = 0.f;
        #pragma unroll
        for (int i = 0; i < 16; i++){
            const uint4 hq = hr[i];
            const uint4 wq = wr[i];
            a0 = dot2f(us2h2(hq.x), us2h2(wq.x), a0);
            a1 = dot2f(us2h2(hq.y), us2h2(wq.y), a1);
            a0 = dot2f(us2h2(hq.z), us2h2(wq.z), a0);
            a1 = dot2f(us2h2(hq.w), us2h2(wq.w), a1);
        }
        zs_out[(t*BATCH + b)*N_CONF + zi] = a0 + a1 + b_z[zi];
    }
}

// ---------------- W1 prepack: f32 -> f16 B-fragments in ws ----------------
__global__ __launch_bounds__(256) void prepack_w1(const float* __restrict__ dW1,
                                                  _Float16* __restrict__ wsh)
{
    const int tid = blockIdx.x*256 + threadIdx.x;   // 228*256 == 57*1024 exactly
    const int treat = tid >> 10;
    const int r     = tid & 1023;
    const int ft    = r >> 7;
    const int ks    = (r >> 6) & 1;
    const int l     = r & 63;
    const int col   = ft*16 + (l & 15);
    const int kb    = ks*32 + ((l >> 4) << 3);
    h8 v;
    #pragma unroll
    for (int j = 0; j < 8; j++){
        const int k = kb + j;
        v[j] = (k < 35) ? (_Float16)dW1[(treat*35 + k)*128 + col] : (_Float16)0.0f;
    }
    *(h8*)(wsh + (size_t)tid*8) = v;
}

// ---------------- MFMA decoder ----------------
__global__ __launch_bounds__(256) void decoder_mfma(
    const float* __restrict__ cc, const float* __restrict__ zs,
    const _Float16* __restrict__ wsh,
    const float* __restrict__ db1, const float* __restrict__ dW2,
    const float* __restrict__ db2, float* __restrict__ preds)
{
    __shared__ alignas(16) _Float16 m_lds[64*72];   // [row][k] k padded to 72

    const int tid  = threadIdx.x;
    const int base = blockIdx.x * 64;
    const int t    = base >> 8;                     // 64-row blocks never cross t

    for (int idx = tid; idx < 64*72; idx += 256){
        const int r = idx / 72;
        const int j = idx - r*72;
        const int n = base + r;
        const int b = n & 255;
        float v = 0.0f;
        if (j < 5)       v = zs[n*N_CONF + j];
        else if (j < 35) v = cc[(b*T_CURN + t)*N_COV + (j - 5)];
        m_lds[r*72 + j] = (_Float16)v;
    }
    __syncthreads();

    const int w    = tid >> 6;
    const int l    = tid & 63;
    const int row  = l & 15;
    const int quad = l >> 4;

    const _Float16* arow = m_lds + (w*16 + row)*72 + quad*8;
    const h8 a0 = *(const h8*)(arow);
    const h8 a1 = *(const h8*)(arow + 32);
    const int nbase = base + w*16 + quad*4;

    for (int treat = 0; treat < 57; treat++){
        const _Float16* bp = wsh + (size_t)treat*8192 + l*8;
        f32x4 pred = {0.0f, 0.0f, 0.0f, 0.0f};
        #pragma unroll
        for (int ft = 0; ft < 8; ft++){
            const h8 b0 = *(const h8*)(bp + ft*1024);
            const h8 b1 = *(const h8*)(bp + ft*1024 + 512);
            f32x4 acc = {0.0f, 0.0f, 0.0f, 0.0f};
            acc = __builtin_amdgcn_mfma_f32_16x16x32_f16(a0, b0, acc, 0, 0, 0);
            acc = __builtin_amdgcn_mfma_f32_16x16x32_f16(a1, b1, acc, 0, 0, 0);
            const int col = ft*16 + row;
            const float hb1 = db1[treat*128 + col];
            const float hw2 = dW2[treat*128 + col];
            #pragma unroll
            for (int r = 0; r < 4; r++){
                float hd = acc[r] + hb1;
                hd = (hd > 0.0f) ? hd : 0.01f*hd;
                pred[r] += hd * hw2;
            }
        }
        #pragma unroll
        for (int r = 0; r < 4; r++){
            float s = pred[r];
            s += __shfl_xor(s, 1);
            s += __shfl_xor(s, 2);
            s += __shfl_xor(s, 4);
            s += __shfl_xor(s, 8);
            pred[r] = s;
        }
        if (row == 0){
            const float b2 = db2[treat];
            #pragma unroll
            for (int r = 0; r < 4; r++)
                preds[(size_t)(nbase + r)*N_TREAT + treat] = pred[r] + b2;
        }
    }
}

// ---------------- fp32 fallback decoder (only if ws too small) ----------------
__global__ __launch_bounds__(256) void decoder_fallback(
    const float* __restrict__ cc, const float* __restrict__ zs,
    const float* __restrict__ dW1, const float* __restrict__ db1,
    const float* __restrict__ dW2, const float* __restrict__ db2,
    float* __restrict__ preds)
{
    const int t     = blockIdx.x;
    const int treat = blockIdx.y;
    const int tid   = threadIdx.x;

    __shared__ alignas(16) float w1t[128*36];
    __shared__ float b1s[128];
    __shared__ float w2s[128];

    for (int it = tid; it < 35*128; it += 256){
        const int cidx = it >> 7;
        const int f    = it & 127;
        w1t[f*36 + cidx] = dW1[(treat*35 + cidx)*128 + f];
    }
    if (tid < 128){
        b1s[tid] = db1[treat*128 + tid];
        w2s[tid] = dW2[treat*128 + tid];
        w1t[tid*36 + 35] = 0.0f;
    }
    __syncthreads();

    const int n = t*BATCH + tid;
    float m[36];
    #pragma unroll
    for (int j = 0; j < N_CONF; j++) m[j] = zs[n*N_CONF + j];
    #pragma unroll
    for (int j = 0; j < N_COV; j++)  m[N_CONF + j] = cc[(tid*T_CURN + t)*N_COV + j];
    m[35] = 0.0f;

    const float b2 = db2[treat];
    float pred = 0.0f;
    for (int f = 0; f < 128; f++){
        float a = b1s[f];
        const float4* wr = (const float4*)(w1t + f*36);
        #pragma unroll
        for (int cq = 0; cq < 9; cq++){
            const float4 v = wr[cq];
            a += m[cq*4+0]*v.x + m[cq*4+1]*v.y + m[cq*4+2]*v.z + m[cq*4+3]*v.w;
        }
        a = (a > 0.0f) ? a : 0.01f*a;
        pred += a * w2s[f];
    }
    preds[n*N_TREAT + treat] = pred + b2;
}

extern "C" void kernel_launch(void* const* d_in, const int* in_sizes, int n_in,
                              void* d_out, int out_size, void* d_ws, size_t ws_size,
                              hipStream_t stream)
{
    const float* pc   = (const float*)d_in[0];
    const float* pt   = (const float*)d_in[1];
    const float* cc   = (const float*)d_in[2];
    const float* init = (const float*)d_in[3];
    const float* h0   = (const float*)d_in[4];
    const float* c0   = (const float*)d_in[5];
    const float* z0   = (const float*)d_in[6];
    const float* W_ih = (const float*)d_in[7];
    const float* W_hh = (const float*)d_in[8];
    const float* b_ih = (const float*)d_in[9];
    const float* b_hh = (const float*)d_in[10];
    const float* W_z  = (const float*)d_in[11];
    const float* b_z  = (const float*)d_in[12];
    const float* dW1  = (const float*)d_in[13];
    const float* db1  = (const float*)d_in[14];
    const float* dW2  = (const float*)d_in[15];
    const float* db2  = (const float*)d_in[16];

    float* preds = (float*)d_out;
    float* zs    = (float*)d_out + CONF_OFF;

    const bool use_mfma = (ws_size >= (size_t)WS_NEED);

    if (use_mfma)
        prepack_w1<<<228, 256, 0, stream>>>(dW1, (_Float16*)d_ws);

    lstm_scan<<<BATCH, 1024, 0, stream>>>(pc, pt, init, h0, c0, z0,
                                          W_ih, W_hh, b_ih, b_hh, W_z, b_z, zs);

    if (use_mfma)
        decoder_mfma<<<516, 256, 0, stream>>>(cc, zs, (const _Float16*)d_ws,
                                              db1, dW2, db2, preds);
    else
        decoder_fallback<<<dim3(T_CURN, N_TREAT), 256, 0, stream>>>(
            cc, zs, dW1, db1, dW2, db2, preds);
}

// Round 4
// 224.308 us; speedup vs baseline: 2.7636x; 1.1424x over previous
//
#include <hip/hip_runtime.h>
#include <stdint.h>

#define BATCH 256
#define T_PREVN 128
#define T_CURN 129
#define N_COV 30
#define N_TREAT 57
#define N_CONF 5
#define HID 128
#define D_IN 87
#define D_CELL 92
#define GATES 512            // 4*H
#define PRED_N (T_CURN*BATCH)        // 33024
#define CONF_OFF (PRED_N*N_TREAT)    // 1882368
#define WS_NEED (57*8*2*64*8*2)              // 933888 B: f16 W1 B-fragments
#define MT_ELEMS (PRED_N*40)                 // 1320960 halfs
#define WS_NEED2 (WS_NEED + MT_ELEMS*2)      // + 2641920 B: mT[n][40] f16

typedef _Float16 h2 __attribute__((ext_vector_type(2)));
typedef _Float16 h4 __attribute__((ext_vector_type(4)));
typedef _Float16 h8 __attribute__((ext_vector_type(8)));
typedef float f32x4 __attribute__((ext_vector_type(4)));

__device__ inline float rcp_fast(float x){
#if __has_builtin(__builtin_amdgcn_rcpf)
    return __builtin_amdgcn_rcpf(x);
#else
    return 1.0f / x;
#endif
}
__device__ inline float sigmoid_f(float x){ return rcp_fast(1.0f + __expf(-x)); }
__device__ inline float tanh_f(float x){ return 1.0f - 2.0f*rcp_fast(1.0f + __expf(2.0f*x)); }

__device__ inline float dot2f(h2 a, h2 b, float c){
#if __has_builtin(__builtin_amdgcn_fdot2)
    return __builtin_amdgcn_fdot2(a, b, c, false);
#else
    return c + (float)a.x*(float)b.x + (float)a.y*(float)b.y;
#endif
}
__device__ inline unsigned short f2us(float v){
    _Float16 h = (_Float16)v;
    return __builtin_bit_cast(unsigned short, h);
}
__device__ inline h2 us2h2(unsigned int u){
    return __builtin_bit_cast(h2, u);
}

// ---------------- LSTM scan (R3 structure; optional mT z-col write) ----------------
__global__ __launch_bounds__(1024, 4) void lstm_scan(
    const float* __restrict__ pc, const float* __restrict__ pt,
    const float* __restrict__ init_input, const float* __restrict__ h0,
    const float* __restrict__ c0, const float* __restrict__ z0,
    const float* __restrict__ W_ih, const float* __restrict__ W_hh,
    const float* __restrict__ b_ih, const float* __restrict__ b_hh,
    const float* __restrict__ W_z, const float* __restrict__ b_z,
    float* __restrict__ zs_out, _Float16* __restrict__ mT)
{
    const int b   = blockIdx.x;
    const int tid = threadIdx.x;
    const int g   = tid >> 1;      // gate 0..511
    const int hf  = tid & 1;       // k-half

    __shared__ alignas(16) unsigned short v16[224];
    __shared__ alignas(16) unsigned short xall[T_CURN*88];
    __shared__ alignas(16) unsigned short hall[T_CURN*136];
    __shared__ alignas(16) float gbuf[GATES];
    __shared__ alignas(16) _Float16 wz16[5*HID];
    __shared__ float z0c[5];

    float wzg[5];
    #pragma unroll
    for (int z = 0; z < 5; z++) wzg[z] = W_ih[g*D_CELL + 87 + z];

    float be = b_ih[g] + b_hh[g];
    #pragma unroll
    for (int z = 0; z < 5; z++) be += wzg[z] * b_z[z];

    h2 w[56];
    if (hf == 0){
        #pragma unroll
        for (int i = 0; i < 43; i++){
            h2 p; p.x = (_Float16)W_ih[g*D_CELL + 2*i];
                  p.y = (_Float16)W_ih[g*D_CELL + 2*i + 1];
            w[i] = p;
        }
        { h2 p; p.x = (_Float16)W_ih[g*D_CELL + 86]; p.y = (_Float16)0.0f; w[43] = p; }
        #pragma unroll
        for (int i = 44; i < 56; i++){
            const int u = 2*(i - 44);
            float f0 = W_hh[g*HID + u], f1 = W_hh[g*HID + u + 1];
            #pragma unroll
            for (int z = 0; z < 5; z++){
                f0 += wzg[z]*W_z[z*HID + u];
                f1 += wzg[z]*W_z[z*HID + u + 1];
            }
            h2 p; p.x = (_Float16)f0; p.y = (_Float16)f1;
            w[i] = p;
        }
    } else {
        #pragma unroll
        for (int i = 0; i < 52; i++){
            const int u = 24 + 2*i;
            float f0 = W_hh[g*HID + u], f1 = W_hh[g*HID + u + 1];
            #pragma unroll
            for (int z = 0; z < 5; z++){
                f0 += wzg[z]*W_z[z*HID + u];
                f1 += wzg[z]*W_z[z*HID + u + 1];
            }
            h2 p; p.x = (_Float16)f0; p.y = (_Float16)f1;
            w[i] = p;
        }
        #pragma unroll
        for (int i = 52; i < 56; i++){ h2 p; p.x=(_Float16)0.f; p.y=(_Float16)0.f; w[i]=p; }
    }

    for (int idx = tid; idx < T_CURN*88; idx += 1024){
        const int row = idx / 88;
        const int col = idx - row*88;
        float v = 0.0f;
        if (col < D_IN){
            if (row == 0) v = init_input[col];
            else {
                const int tp = row - 1;
                v = (col < N_COV) ? pc[(b*T_PREVN + tp)*N_COV + col]
                                  : pt[(b*T_PREVN + tp)*N_TREAT + (col - N_COV)];
            }
        }
        xall[idx] = f2us(v);
    }

    float c = 0.0f;
    if (tid < HID){ v16[88 + tid] = f2us(h0[tid]); c = c0[tid]; }
    if (tid >= 216 && tid < 224) v16[tid] = 0;

    if (tid < 5){
        float acc0 = 0.0f, acc1 = 0.0f;
        #pragma unroll 8
        for (int u = 0; u < HID; u += 2){
            acc0 += W_z[tid*HID + u]     * h0[u];
            acc1 += W_z[tid*HID + u + 1] * h0[u + 1];
        }
        z0c[tid] = z0[tid] - b_z[tid] - (acc0 + acc1);
    }
    __syncthreads();

    if (tid >= 128 && tid < 216) v16[tid - 128] = xall[tid - 128];
    float b0 = be;
    #pragma unroll
    for (int z = 0; z < 5; z++) b0 += wzg[z] * z0c[z];
    __syncthreads();

    const unsigned short* vbase = v16 + hf*112;
    for (int t = 0; t < T_CURN; t++){
        float a0 = 0.f, a1 = 0.f, a2 = 0.f, a3 = 0.f;
        #pragma unroll
        for (int i = 0; i < 14; i++){
            const uint4 q = *(const uint4*)(vbase + i*8);
            a0 = dot2f(w[4*i+0], us2h2(q.x), a0);
            a1 = dot2f(w[4*i+1], us2h2(q.y), a1);
            a2 = dot2f(w[4*i+2], us2h2(q.z), a2);
            a3 = dot2f(w[4*i+3], us2h2(q.w), a3);
        }
        float s = (a0 + a1) + (a2 + a3);
        s += __shfl_xor(s, 1);
        if (hf == 0) gbuf[g] = s + ((t == 0) ? b0 : be);
        __syncthreads();

        if (tid < HID){
            const float gi = gbuf[tid];
            const float gf = gbuf[128 + tid];
            const float gg = gbuf[256 + tid];
            const float go = gbuf[384 + tid];
            c = sigmoid_f(gf)*c + sigmoid_f(gi)*tanh_f(gg);
            const float h = sigmoid_f(go)*tanh_f(c);
            const unsigned short hu = f2us(h);
            v16[88 + tid] = hu;
            hall[t*136 + tid] = hu;
        } else if (tid < 216){
            if (t < T_PREVN) v16[tid - 128] = xall[(t + 1)*88 + (tid - 128)];
        }
        __syncthreads();
    }

    for (int i = tid; i < 5*HID; i += 1024) wz16[i] = (_Float16)W_z[i];
    __syncthreads();

    if (tid < T_CURN*N_CONF){
        const int t  = tid / 5;
        const int zi = tid - t*5;
        const uint4* hr = (const uint4*)(hall + t*136);
        const uint4* wr = (const uint4*)(wz16 + zi*HID);
        float a0 = 0.f, a1 = 0.f;
        #pragma unroll
        for (int i = 0; i < 16; i++){
            const uint4 hq = hr[i];
            const uint4 wq = wr[i];
            a0 = dot2f(us2h2(hq.x), us2h2(wq.x), a0);
            a1 = dot2f(us2h2(hq.y), us2h2(wq.y), a1);
            a0 = dot2f(us2h2(hq.z), us2h2(wq.z), a0);
            a1 = dot2f(us2h2(hq.w), us2h2(wq.w), a1);
        }
        const float z = a0 + a1 + b_z[zi];
        const int n = t*BATCH + b;
        zs_out[(size_t)n*N_CONF + zi] = z;
        if (mT) mT[(size_t)n*40 + zi] = (_Float16)z;
    }
}

// ---------------- W1 prepack: f32 -> f16 B-fragments in ws ----------------
__global__ __launch_bounds__(256) void prepack_w1(const float* __restrict__ dW1,
                                                  _Float16* __restrict__ wsh)
{
    const int tid = blockIdx.x*256 + threadIdx.x;   // 228*256 == 57*1024 exactly
    const int treat = tid >> 10;
    const int r     = tid & 1023;
    const int ft    = r >> 7;
    const int ks    = (r >> 6) & 1;
    const int l     = r & 63;
    const int col   = ft*16 + (l & 15);
    const int kb    = ks*32 + ((l >> 4) << 3);
    h8 v;
    #pragma unroll
    for (int j = 0; j < 8; j++){
        const int k = kb + j;
        v[j] = (k < 35) ? (_Float16)dW1[(treat*35 + k)*128 + col] : (_Float16)0.0f;
    }
    *(h8*)(wsh + (size_t)tid*8) = v;
}

// ---------------- mT cov fill: mT[n][c] = cc transposed (c=5..34), 0 pad (35..39) --------
__global__ __launch_bounds__(256) void mt_cov(const float* __restrict__ cc,
                                              _Float16* __restrict__ mT)
{
    const int tid = blockIdx.x*256 + threadIdx.x;   // 5160*256 == 33024*40 exactly
    const int n = tid / 40;
    const int c = tid - n*40;
    if (c < 5) return;                               // scan writes z cols
    float v = 0.0f;
    if (c < 35){
        const int b = n & 255;
        const int t = n >> 8;
        v = cc[(b*T_CURN + t)*N_COV + (c - 5)];
    }
    mT[tid] = (_Float16)v;
}

// ---------------- treat-stationary MFMA decoder ----------------
// block = (treat, row-group of 258 tiles), 4 waves; wave owns B-frags in regs,
// streams 16-row tiles: 1 b128 + 1 b64 A-load, 16 MFMA, in-lane epilogue.
__global__ __launch_bounds__(256, 2) void decoder_treat(
    const _Float16* __restrict__ mT, const _Float16* __restrict__ wsh,
    const float* __restrict__ db1, const float* __restrict__ dW2,
    const float* __restrict__ db2, float* __restrict__ preds)
{
    const int treat = blockIdx.x;
    const int rg    = blockIdx.y;
    const int w     = threadIdx.x >> 6;
    const int l     = threadIdx.x & 63;
    const int q     = l >> 4;
    const int r16   = l & 15;

    h8 bf0[8], bf1[8];
    const _Float16* bp = wsh + (size_t)treat*8192 + l*8;
    #pragma unroll
    for (int ft = 0; ft < 8; ft++){
        bf0[ft] = *(const h8*)(bp + ft*1024);
        bf1[ft] = *(const h8*)(bp + ft*1024 + 512);
    }
    float b1r[8], w2r[8], w2c[8];
    #pragma unroll
    for (int ft = 0; ft < 8; ft++){
        b1r[ft] = db1[treat*128 + ft*16 + r16];
        w2r[ft] = dW2[treat*128 + ft*16 + r16];
        w2c[ft] = 0.01f * w2r[ft];
    }
    const float b2 = db2[treat];

    const int tend = (rg + 1)*258;
    for (int tile = rg*258 + w; tile < tend; tile += 4){
        const int n = tile*16 + r16;
        const _Float16* mrow = mT + (size_t)n*40;
        const h8 a0 = *(const h8*)(mrow + q*8);
        h8 a1 = {};
        if (q == 0){
            const h4 t4 = *(const h4*)(mrow + 32);   // cols 32,33,34,pad35
            a1[0] = t4[0]; a1[1] = t4[1]; a1[2] = t4[2]; a1[3] = t4[3];
        }

        f32x4 pred = {0.f, 0.f, 0.f, 0.f};
        #pragma unroll
        for (int ft = 0; ft < 8; ft++){
            f32x4 acc = {b1r[ft], b1r[ft], b1r[ft], b1r[ft]};
            acc = __builtin_amdgcn_mfma_f32_16x16x32_f16(a0, bf0[ft], acc, 0, 0, 0);
            acc = __builtin_amdgcn_mfma_f32_16x16x32_f16(a1, bf1[ft], acc, 0, 0, 0);
            #pragma unroll
            for (int r = 0; r < 4; r++){
                const float a  = acc[r];
                const float mx = fmaxf(a, 0.0f);
                const float mn = fminf(a, 0.0f);
                pred[r] += mx*w2r[ft] + mn*w2c[ft];
            }
        }
        #pragma unroll
        for (int r = 0; r < 4; r++){
            float s = pred[r];
            s += __shfl_xor(s, 1);
            s += __shfl_xor(s, 2);
            s += __shfl_xor(s, 4);
            s += __shfl_xor(s, 8);
            pred[r] = s;
        }
        if (r16 == 0){
            #pragma unroll
            for (int r = 0; r < 4; r++)
                preds[(size_t)(tile*16 + q*4 + r)*N_TREAT + treat] = pred[r] + b2;
        }
    }
}

// ---------------- R2 MFMA decoder (fallback if ws fits W1 only) ----------------
__global__ __launch_bounds__(256) void decoder_mfma(
    const float* __restrict__ cc, const float* __restrict__ zs,
    const _Float16* __restrict__ wsh,
    const float* __restrict__ db1, const float* __restrict__ dW2,
    const float* __restrict__ db2, float* __restrict__ preds)
{
    __shared__ alignas(16) _Float16 m_lds[64*72];

    const int tid  = threadIdx.x;
    const int base = blockIdx.x * 64;
    const int t    = base >> 8;

    for (int idx = tid; idx < 64*72; idx += 256){
        const int r = idx / 72;
        const int j = idx - r*72;
        const int n = base + r;
        const int b = n & 255;
        float v = 0.0f;
        if (j < 5)       v = zs[n*N_CONF + j];
        else if (j < 35) v = cc[(b*T_CURN + t)*N_COV + (j - 5)];
        m_lds[r*72 + j] = (_Float16)v;
    }
    __syncthreads();

    const int w    = tid >> 6;
    const int l    = tid & 63;
    const int row  = l & 15;
    const int quad = l >> 4;

    const _Float16* arow = m_lds + (w*16 + row)*72 + quad*8;
    const h8 a0 = *(const h8*)(arow);
    const h8 a1 = *(const h8*)(arow + 32);
    const int nbase = base + w*16 + quad*4;

    for (int treat = 0; treat < 57; treat++){
        const _Float16* bp = wsh + (size_t)treat*8192 + l*8;
        f32x4 pred = {0.0f, 0.0f, 0.0f, 0.0f};
        #pragma unroll
        for (int ft = 0; ft < 8; ft++){
            const h8 b0 = *(const h8*)(bp + ft*1024);
            const h8 b1 = *(const h8*)(bp + ft*1024 + 512);
            f32x4 acc = {0.0f, 0.0f, 0.0f, 0.0f};
            acc = __builtin_amdgcn_mfma_f32_16x16x32_f16(a0, b0, acc, 0, 0, 0);
            acc = __builtin_amdgcn_mfma_f32_16x16x32_f16(a1, b1, acc, 0, 0, 0);
            const int col = ft*16 + row;
            const float hb1 = db1[treat*128 + col];
            const float hw2 = dW2[treat*128 + col];
            #pragma unroll
            for (int r = 0; r < 4; r++){
                float hd = acc[r] + hb1;
                hd = (hd > 0.0f) ? hd : 0.01f*hd;
                pred[r] += hd * hw2;
            }
        }
        #pragma unroll
        for (int r = 0; r < 4; r++){
            float s = pred[r];
            s += __shfl_xor(s, 1);
            s += __shfl_xor(s, 2);
            s += __shfl_xor(s, 4);
            s += __shfl_xor(s, 8);
            pred[r] = s;
        }
        if (row == 0){
            const float b2 = db2[treat];
            #pragma unroll
            for (int r = 0; r < 4; r++)
                preds[(size_t)(nbase + r)*N_TREAT + treat] = pred[r] + b2;
        }
    }
}

// ---------------- fp32 fallback decoder (only if ws tiny) ----------------
__global__ __launch_bounds__(256) void decoder_fallback(
    const float* __restrict__ cc, const float* __restrict__ zs,
    const float* __restrict__ dW1, const float* __restrict__ db1,
    const float* __restrict__ dW2, const float* __restrict__ db2,
    float* __restrict__ preds)
{
    const int t     = blockIdx.x;
    const int treat = blockIdx.y;
    const int tid   = threadIdx.x;

    __shared__ alignas(16) float w1t[128*36];
    __shared__ float b1s[128];
    __shared__ float w2s[128];

    for (int it = tid; it < 35*128; it += 256){
        const int cidx = it >> 7;
        const int f    = it & 127;
        w1t[f*36 + cidx] = dW1[(treat*35 + cidx)*128 + f];
    }
    if (tid < 128){
        b1s[tid] = db1[treat*128 + tid];
        w2s[tid] = dW2[treat*128 + tid];
        w1t[tid*36 + 35] = 0.0f;
    }
    __syncthreads();

    const int n = t*BATCH + tid;
    float m[36];
    #pragma unroll
    for (int j = 0; j < N_CONF; j++) m[j] = zs[n*N_CONF + j];
    #pragma unroll
    for (int j = 0; j < N_COV; j++)  m[N_CONF + j] = cc[(tid*T_CURN + t)*N_COV + j];
    m[35] = 0.0f;

    const float b2 = db2[treat];
    float pred = 0.0f;
    for (int f = 0; f < 128; f++){
        float a = b1s[f];
        const float4* wr = (const float4*)(w1t + f*36);
        #pragma unroll
        for (int cq = 0; cq < 9; cq++){
            const float4 v = wr[cq];
            a += m[cq*4+0]*v.x + m[cq*4+1]*v.y + m[cq*4+2]*v.z + m[cq*4+3]*v.w;
        }
        a = (a > 0.0f) ? a : 0.01f*a;
        pred += a * w2s[f];
    }
    preds[n*N_TREAT + treat] = pred + b2;
}

extern "C" void kernel_launch(void* const* d_in, const int* in_sizes, int n_in,
                              void* d_out, int out_size, void* d_ws, size_t ws_size,
                              hipStream_t stream)
{
    const float* pc   = (const float*)d_in[0];
    const float* pt   = (const float*)d_in[1];
    const float* cc   = (const float*)d_in[2];
    const float* init = (const float*)d_in[3];
    const float* h0   = (const float*)d_in[4];
    const float* c0   = (const float*)d_in[5];
    const float* z0   = (const float*)d_in[6];
    const float* W_ih = (const float*)d_in[7];
    const float* W_hh = (const float*)d_in[8];
    const float* b_ih = (const float*)d_in[9];
    const float* b_hh = (const float*)d_in[10];
    const float* W_z  = (const float*)d_in[11];
    const float* b_z  = (const float*)d_in[12];
    const float* dW1  = (const float*)d_in[13];
    const float* db1  = (const float*)d_in[14];
    const float* dW2  = (const float*)d_in[15];
    const float* db2  = (const float*)d_in[16];

    float* preds = (float*)d_out;
    float* zs    = (float*)d_out + CONF_OFF;

    const bool ws_full = (ws_size >= (size_t)WS_NEED2);
    const bool ws_w1   = (ws_size >= (size_t)WS_NEED);

    _Float16* wsh = (_Float16*)d_ws;
    _Float16* mT  = (_Float16*)((char*)d_ws + WS_NEED);

    if (ws_w1)
        prepack_w1<<<228, 256, 0, stream>>>(dW1, wsh);
    if (ws_full)
        mt_cov<<<5160, 256, 0, stream>>>(cc, mT);

    lstm_scan<<<BATCH, 1024, 0, stream>>>(pc, pt, init, h0, c0, z0,
                                          W_ih, W_hh, b_ih, b_hh, W_z, b_z,
                                          zs, ws_full ? mT : (_Float16*)nullptr);

    if (ws_full)
        decoder_treat<<<dim3(N_TREAT, 8), 256, 0, stream>>>(mT, wsh, db1, dW2, db2, preds);
    else if (ws_w1)
        decoder_mfma<<<516, 256, 0, stream>>>(cc, zs, wsh, db1, dW2, db2, preds);
    else
        decoder_fallback<<<dim3(T_CURN, N_TREAT), 256, 0, stream>>>(
            cc, zs, dW1, db1, dW2, db2, preds);
}